// Round 2
// 718.405 us; speedup vs baseline: 1.0926x; 1.0926x over previous
//
#include <hip/hip_runtime.h>
#include <hip/hip_bf16.h>
#include <cstdint>
#include <cstddef>

typedef __bf16 bf16_t;
typedef __bf16 bf16x4 __attribute__((ext_vector_type(4)));
typedef __bf16 bf16x8 __attribute__((ext_vector_type(8)));
typedef float f32x4 __attribute__((ext_vector_type(4)));

#define MFMA16(a,b,c) __builtin_amdgcn_mfma_f32_16x16x32_bf16((a),(b),(c),0,0,0)

// B=4, S=2048, D=512, H=8 -> groups G=32, L=2048, PHD=64, rows M=8192
// grouped flat: elem[g][t][p] = flat[g*131072 + t*64 + p]   (torch .view semantics:
// pure reinterpretation of the contiguous [B,S,D] buffer — NOT a per-head column split)
// out (f32) = [output (4194304), attn (32*2048*2048)]

// ---------------- GEMM core: C[8192,512] = X @ W^T + bias (+ f32 residual) -> bf16 ----------------
template<bool XF32>
__device__ __forceinline__ void gemm_core(const void* __restrict__ Xp,
                                          const float* __restrict__ W,
                                          const float* __restrict__ bias,
                                          const float* __restrict__ residual,
                                          bf16_t* __restrict__ out)
{
    __shared__ __align__(16) bf16_t As[128*32];
    __shared__ __align__(16) bf16_t Bs[128*32];
    const int tid  = threadIdx.x;
    const int lane = tid & 63;
    const int w    = tid >> 6;
    const int wm   = (w & 1) * 64;
    const int wn   = (w >> 1) * 64;
    const int bm   = blockIdx.y * 128;
    const int bn   = blockIdx.x * 128;
    const int fr   = lane & 15;
    const int fq8  = (lane >> 4) * 8;

    f32x4 acc[4][4];
#pragma unroll
    for (int i = 0; i < 4; i++)
#pragma unroll
        for (int j = 0; j < 4; j++)
            acc[i][j] = (f32x4){0.f, 0.f, 0.f, 0.f};

    const int srow = tid >> 2;          // 0..63
    const int scol = (tid & 3) * 8;     // 0,8,16,24

    for (int k0 = 0; k0 < 512; k0 += 32) {
        __syncthreads();
        if constexpr (XF32) {
            const float* X = (const float*)Xp;
#pragma unroll
            for (int c = 0; c < 4; c++) {
                const int chunk = c*256 + tid;   // 0..1023
                const int row = chunk >> 3;      // 0..127
                const int cc  = (chunk & 7) * 4; // 0..28
                f32x4 xv = *(const f32x4*)(X + (size_t)(bm + row)*512 + k0 + cc);
                bf16x4 b = {(bf16_t)xv[0], (bf16_t)xv[1], (bf16_t)xv[2], (bf16_t)xv[3]};
                *(bf16x4*)(&As[row*32 + cc]) = b;
            }
        } else {
            const bf16_t* X = (const bf16_t*)Xp;
            *(bf16x8*)(&As[srow*32 + scol])      = *(const bf16x8*)(X + (size_t)(bm + srow)*512      + k0 + scol);
            *(bf16x8*)(&As[(64+srow)*32 + scol]) = *(const bf16x8*)(X + (size_t)(bm + 64 + srow)*512 + k0 + scol);
        }
#pragma unroll
        for (int c = 0; c < 4; c++) {
            const int chunk = c*256 + tid;
            const int row = chunk >> 3;
            const int cc  = (chunk & 7) * 4;
            f32x4 wv = *(const f32x4*)(W + (size_t)(bn + row)*512 + k0 + cc);
            bf16x4 b = {(bf16_t)wv[0], (bf16_t)wv[1], (bf16_t)wv[2], (bf16_t)wv[3]};
            *(bf16x4*)(&Bs[row*32 + cc]) = b;
        }
        __syncthreads();
        bf16x8 af[4], bfv[4];
#pragma unroll
        for (int i = 0; i < 4; i++) {
            af[i]  = *(const bf16x8*)(&As[(wm + i*16 + fr)*32 + fq8]);
            bfv[i] = *(const bf16x8*)(&Bs[(wn + i*16 + fr)*32 + fq8]);
        }
#pragma unroll
        for (int i = 0; i < 4; i++)
#pragma unroll
            for (int j = 0; j < 4; j++)
                acc[i][j] = MFMA16(af[i], bfv[j], acc[i][j]);
    }

    const int q4 = (lane >> 4) * 4;
#pragma unroll
    for (int j = 0; j < 4; j++) {
        const int col = bn + wn + j*16 + fr;
        const float bcol = bias[col];
#pragma unroll
        for (int i = 0; i < 4; i++) {
#pragma unroll
            for (int r = 0; r < 4; r++) {
                const int row = bm + wm + i*16 + q4 + r;
                float v = acc[i][j][r] + bcol;
                if (residual) v += residual[(size_t)row*512 + col];
                out[(size_t)row*512 + col] = (bf16_t)v;
            }
        }
    }
}

__global__ __launch_bounds__(256) void gemm_qkv_kernel(
    const float* __restrict__ Xq, const float* __restrict__ Xk, const float* __restrict__ Xv,
    const float* __restrict__ Wq, const float* __restrict__ Wk, const float* __restrict__ Wv,
    const float* __restrict__ bq, const float* __restrict__ bk, const float* __restrict__ bv,
    bf16_t* __restrict__ Oq, bf16_t* __restrict__ Ok, bf16_t* __restrict__ Ov)
{
    const int z = blockIdx.z;
    const float* X    = (z == 0) ? Xq : (z == 1) ? Xk : Xv;
    const float* W    = (z == 0) ? Wq : (z == 1) ? Wk : Wv;
    const float* bias = (z == 0) ? bq : (z == 1) ? bk : bv;
    bf16_t* out       = (z == 0) ? Oq : (z == 1) ? Ok : Ov;
    gemm_core<true>(X, W, bias, nullptr, out);
}

__global__ __launch_bounds__(256) void gemm_o_kernel(
    const bf16_t* __restrict__ ctx, const float* __restrict__ Wo,
    const float* __restrict__ bo, const float* __restrict__ residual,
    bf16_t* __restrict__ xout)
{
    gemm_core<false>(ctx, Wo, bo, residual, xout);
}

// ---------------- V transpose per group: vt[g][p][t] = v[g][t][p] (bf16) ----------------
// v is the flat GEMM output reinterpreted in grouped layout — faithful to torch .view.
__global__ __launch_bounds__(256) void transpose_v_kernel(const bf16_t* __restrict__ v,
                                                          bf16_t* __restrict__ vt)
{
    __shared__ bf16_t tile[64*72];
    const int g  = blockIdx.y;
    const int t0 = blockIdx.x * 64;
    const int tid = threadIdx.x;
    const size_t gbase = (size_t)g * 131072;
#pragma unroll
    for (int c = 0; c < 2; c++) {
        const int chunk = c*256 + tid;   // 0..511
        const int row = chunk >> 3;      // t local 0..63
        const int cc  = (chunk & 7) * 8; // p col
        *(bf16x8*)(&tile[row*72 + cc]) = *(const bf16x8*)(v + gbase + (size_t)(t0 + row)*64 + cc);
    }
    __syncthreads();
#pragma unroll
    for (int c = 0; c < 2; c++) {
        const int chunk = c*256 + tid;
        const int p  = chunk >> 3;        // 0..63
        const int tc = (chunk & 7) * 8;   // t chunk base
        bf16x8 vv;
#pragma unroll
        for (int i = 0; i < 8; i++) vv[i] = tile[(tc + i)*72 + p];
        *(bf16x8*)(vt + gbase + (size_t)p*2048 + t0 + tc) = vv;
    }
}

// ---------------- Attention: per (group, 128-row Q tile) ----------------
__global__ __launch_bounds__(512) void attn_kernel(
    const bf16_t* __restrict__ Q, const bf16_t* __restrict__ K,
    const bf16_t* __restrict__ VT,
    float* __restrict__ attn, bf16_t* __restrict__ ctx)
{
    // 64 KB total -> 2 blocks/CU
    __shared__ __align__(16) bf16_t kb [128*64];   // phase1: K buf A   | phase2: K tile
    __shared__ __align__(16) bf16_t kb2[128*64];   // phase1: K buf B   | phase2: Vt tile
    __shared__ __align__(16) bf16_t pb [128*128];  // prologue: Q stage | phase2: P tile (wave-local!)

    const int tid  = threadIdx.x;
    const int lane = tid & 63;
    const int w    = tid >> 6;    // wave 0..7 -> Q rows w*16..+15
    const int fr   = lane & 15;
    const int quad = lane >> 4;
    const int g    = blockIdx.y;
    const int qt   = blockIdx.x;
    const size_t gbase = (size_t)g * 131072;

    const int c0 = tid;           // staging chunk ids
    const int c1 = 512 + tid;

    // ---- stage Q tile [128][64] into pb (kb-style swizzle), pull frags to regs ----
    {
        const int r0 = c0 >> 3, k0c = c0 & 7;
        const int r1 = c1 >> 3, k1c = c1 & 7;
        *(bf16x8*)(&pb[r0*64 + ((k0c ^ (r0 & 7)) << 3)]) =
            *(const bf16x8*)(Q + gbase + (size_t)(qt*128 + r0)*64 + k0c*8);
        *(bf16x8*)(&pb[r1*64 + ((k1c ^ (r1 & 7)) << 3)]) =
            *(const bf16x8*)(Q + gbase + (size_t)(qt*128 + r1)*64 + k1c*8);
    }
    __syncthreads();
    bf16x8 qf[2];
#pragma unroll
    for (int ks = 0; ks < 2; ks++) {
        const int row = w*16 + fr;
        const int cs = (ks*4 + quad) ^ (fr & 7);
        qf[ks] = *(const bf16x8*)(&pb[row*64 + (cs << 3)]);
    }
    // stage K(0) into kb (no hazard: different buffer than pb)
    {
        const int r0 = c0 >> 3, k0c = c0 & 7;
        const int r1 = c1 >> 3, k1c = c1 & 7;
        *(bf16x8*)(&kb[r0*64 + ((k0c ^ (r0 & 7)) << 3)]) =
            *(const bf16x8*)(K + gbase + (size_t)r0*64 + k0c*8);
        *(bf16x8*)(&kb[r1*64 + ((k1c ^ (r1 & 7)) << 3)]) =
            *(const bf16x8*)(K + gbase + (size_t)r1*64 + k1c*8);
    }
    __syncthreads();

    const float cfac = 0.06376904269107617f;  // log2(e) / sqrt(512)
    float lsum[4] = {0.f, 0.f, 0.f, 0.f};

    // ---- phase 1: row sums of 2^(s*cfac), double-buffered K ----
    for (int kt = 0; kt < 16; kt++) {
        bf16_t* cur = (kt & 1) ? kb2 : kb;
        bf16_t* nxt = (kt & 1) ? kb  : kb2;
        bf16x8 kr0, kr1;
        if (kt < 15) {  // issue next-tile loads early (latency hides under MFMA)
            kr0 = *(const bf16x8*)(K + gbase + (size_t)((kt+1)*128 + (c0 >> 3))*64 + (c0 & 7)*8);
            kr1 = *(const bf16x8*)(K + gbase + (size_t)((kt+1)*128 + (c1 >> 3))*64 + (c1 & 7)*8);
        }
#pragma unroll
        for (int n = 0; n < 8; n++) {
            const int rk = n*16 + fr;
            f32x4 s = (f32x4){0.f, 0.f, 0.f, 0.f};
#pragma unroll
            for (int ks = 0; ks < 2; ks++) {
                const int cs = (ks*4 + quad) ^ (fr & 7);
                bf16x8 bv = *(const bf16x8*)(&cur[rk*64 + (cs << 3)]);
                s = MFMA16(qf[ks], bv, s);
            }
#pragma unroll
            for (int r = 0; r < 4; r++)
                lsum[r] += exp2f(s[r] * cfac);
        }
        if (kt < 15) {
            const int r0 = c0 >> 3, k0c = c0 & 7;
            const int r1 = c1 >> 3, k1c = c1 & 7;
            *(bf16x8*)(&nxt[r0*64 + ((k0c ^ (r0 & 7)) << 3)]) = kr0;
            *(bf16x8*)(&nxt[r1*64 + ((k1c ^ (r1 & 7)) << 3)]) = kr1;
        }
        __syncthreads();
    }

    float rinv[4];
#pragma unroll
    for (int r = 0; r < 4; r++) {
        float l = lsum[r];
        l += __shfl_xor(l, 1);
        l += __shfl_xor(l, 2);
        l += __shfl_xor(l, 4);
        l += __shfl_xor(l, 8);
        rinv[r] = 1.f / l;
    }

    f32x4 oacc[4];
#pragma unroll
    for (int i = 0; i < 4; i++) oacc[i] = (f32x4){0.f, 0.f, 0.f, 0.f};

    float* abase = attn + (size_t)g*4194304 + (size_t)(qt*128)*2048;

    // ---- phase 2 prologue: stage K(0)->kb, VT(0)->kb2 ----
    {
        const int r0 = c0 >> 3, k0c = c0 & 7;
        const int r1 = c1 >> 3, k1c = c1 & 7;
        *(bf16x8*)(&kb[r0*64 + ((k0c ^ (r0 & 7)) << 3)]) =
            *(const bf16x8*)(K + gbase + (size_t)r0*64 + k0c*8);
        *(bf16x8*)(&kb[r1*64 + ((k1c ^ (r1 & 7)) << 3)]) =
            *(const bf16x8*)(K + gbase + (size_t)r1*64 + k1c*8);
        const int p0 = c0 >> 4, v0c = c0 & 15;
        const int p1 = c1 >> 4, v1c = c1 & 15;
        *(bf16x8*)(&kb2[p0*128 + ((v0c ^ (p0 & 15)) << 3)]) =
            *(const bf16x8*)(VT + gbase + (size_t)p0*2048 + v0c*8);
        *(bf16x8*)(&kb2[p1*128 + ((v1c ^ (p1 & 15)) << 3)]) =
            *(const bf16x8*)(VT + gbase + (size_t)p1*2048 + v1c*8);
    }
    __syncthreads();

    // ---- phase 2: recompute S, P->LDS (bf16), vectorized attn store, P@V ----
    for (int kt = 0; kt < 16; kt++) {
        bf16x8 kr0, kr1, vr0, vr1;
        if (kt < 15) {  // T14: issue next-tile loads before the compute sections
            kr0 = *(const bf16x8*)(K + gbase + (size_t)((kt+1)*128 + (c0 >> 3))*64 + (c0 & 7)*8);
            kr1 = *(const bf16x8*)(K + gbase + (size_t)((kt+1)*128 + (c1 >> 3))*64 + (c1 & 7)*8);
            vr0 = *(const bf16x8*)(VT + gbase + (size_t)(c0 >> 4)*2048 + (kt+1)*128 + (c0 & 15)*8);
            vr1 = *(const bf16x8*)(VT + gbase + (size_t)(c1 >> 4)*2048 + (kt+1)*128 + (c1 & 15)*8);
        }
        // QK^T + normalized P -> pb (wave-local rows, no barrier needed before use)
#pragma unroll
        for (int n = 0; n < 8; n++) {
            const int rk = n*16 + fr;
            f32x4 s = (f32x4){0.f, 0.f, 0.f, 0.f};
#pragma unroll
            for (int ks = 0; ks < 2; ks++) {
                const int cs = (ks*4 + quad) ^ (fr & 7);
                bf16x8 bv = *(const bf16x8*)(&kb[rk*64 + (cs << 3)]);
                s = MFMA16(qf[ks], bv, s);
            }
#pragma unroll
            for (int r = 0; r < 4; r++) {
                const float pv = exp2f(s[r] * cfac) * rinv[r];
                const int prow = w*16 + quad*4 + r;
                const int pcol = n*16 + fr;
                pb[prow*128 + ((((pcol >> 3) ^ (prow & 15)) << 3) | (pcol & 7))] = (bf16_t)pv;
            }
        }
        // coalesced nontemporal attn store: wave reads back its own 16 P rows, row-major
#pragma unroll
        for (int i = 0; i < 8; i++) {
            const int chunk = i*64 + lane;       // 0..511 per wave
            const int rloc  = chunk >> 5;        // 0..15
            const int c4    = chunk & 31;        // f32x4 index within row (128 f32 = 32 x f32x4)
            const int prow  = w*16 + rloc;
            const int pc8   = c4 >> 1;
            const int half  = (c4 & 1) * 4;
            bf16x4 pv4 = *(const bf16x4*)(&pb[prow*128 + (((pc8 ^ (prow & 15)) << 3) | half)]);
            f32x4 o = {(float)pv4[0], (float)pv4[1], (float)pv4[2], (float)pv4[3]};
            __builtin_nontemporal_store(o, (f32x4*)(abase + (size_t)prow*2048 + kt*128 + c4*4));
        }
        // P @ V  (pb rows are wave-own; kb2 staged since last barrier)
#pragma unroll
        for (int ks = 0; ks < 4; ks++) {
            const int prow = w*16 + fr;                    // prow & 15 == fr
            const int cs = (ks*4 + quad) ^ fr;
            bf16x8 af = *(const bf16x8*)(&pb[prow*128 + (cs << 3)]);
#pragma unroll
            for (int np = 0; np < 4; np++) {
                const int vrow = np*16 + fr;               // vrow & 15 == fr
                const int cv = (ks*4 + quad) ^ fr;
                bf16x8 bv = *(const bf16x8*)(&kb2[vrow*128 + (cv << 3)]);
                oacc[np] = MFMA16(af, bv, oacc[np]);
            }
        }
        __syncthreads();   // all waves done reading kb/kb2
        if (kt < 15) {
            const int r0 = c0 >> 3, k0c = c0 & 7;
            const int r1 = c1 >> 3, k1c = c1 & 7;
            *(bf16x8*)(&kb[r0*64 + ((k0c ^ (r0 & 7)) << 3)]) = kr0;
            *(bf16x8*)(&kb[r1*64 + ((k1c ^ (r1 & 7)) << 3)]) = kr1;
            const int p0 = c0 >> 4, v0c = c0 & 15;
            const int p1 = c1 >> 4, v1c = c1 & 15;
            *(bf16x8*)(&kb2[p0*128 + ((v0c ^ (p0 & 15)) << 3)]) = vr0;
            *(bf16x8*)(&kb2[p1*128 + ((v1c ^ (p1 & 15)) << 3)]) = vr1;
            __syncthreads();  // staged buffers ready for next kt
        }
    }

    // ---- write context (grouped flat == standard [8192][512] flat), bf16 ----
    const int q4 = quad * 4;
#pragma unroll
    for (int np = 0; np < 4; np++) {
#pragma unroll
        for (int r = 0; r < 4; r++) {
            const int row = qt*128 + w*16 + q4 + r;
            const int col = np*16 + fr;
            ctx[gbase + (size_t)row*64 + col] = (bf16_t)oacc[np][r];
        }
    }
}

// ---------------- LayerNorm (ddof=1, eps added to std), bf16 x -> f32 out ----------------
__global__ __launch_bounds__(256) void ln_kernel(const bf16_t* __restrict__ x,
                                                 const float* __restrict__ wa,
                                                 const float* __restrict__ wb,
                                                 float* __restrict__ out)
{
    const int tid  = threadIdx.x;
    const int lane = tid & 63;
    const int w    = tid >> 6;
    const int row  = blockIdx.x * 4 + w;

    bf16x8 xv = *(const bf16x8*)(x + (size_t)row*512 + lane*8);
    float f[8];
    float s = 0.f;
#pragma unroll
    for (int i = 0; i < 8; i++) { f[i] = (float)xv[i]; s += f[i]; }
#pragma unroll
    for (int m = 1; m < 64; m <<= 1) s += __shfl_xor(s, m);
    const float mean = s * (1.0f / 512.0f);
    float sq = 0.f;
#pragma unroll
    for (int i = 0; i < 8; i++) { const float d = f[i] - mean; sq += d*d; }
#pragma unroll
    for (int m = 1; m < 64; m <<= 1) sq += __shfl_xor(sq, m);
    const float inv = 1.0f / (sqrtf(sq * (1.0f / 511.0f)) + 1e-9f);

    f32x4 wa0 = *(const f32x4*)(wa + lane*8);
    f32x4 wa1 = *(const f32x4*)(wa + lane*8 + 4);
    f32x4 wb0 = *(const f32x4*)(wb + lane*8);
    f32x4 wb1 = *(const f32x4*)(wb + lane*8 + 4);
    f32x4 o0, o1;
#pragma unroll
    for (int i = 0; i < 4; i++) {
        o0[i] = wa0[i] * (f[i]     - mean) * inv + wb0[i];
        o1[i] = wa1[i] * (f[i + 4] - mean) * inv + wb1[i];
    }
    *(f32x4*)(out + (size_t)row*512 + lane*8)     = o0;
    *(f32x4*)(out + (size_t)row*512 + lane*8 + 4) = o1;
}

// ---------------- launch ----------------
extern "C" void kernel_launch(void* const* d_in, const int* in_sizes, int n_in,
                              void* d_out, int out_size, void* d_ws, size_t ws_size,
                              hipStream_t stream)
{
    (void)in_sizes; (void)n_in; (void)out_size; (void)ws_size;
    const float* key   = (const float*)d_in[0];
    const float* value = (const float*)d_in[1];
    const float* query = (const float*)d_in[2];
    const float* Wq = (const float*)d_in[3];
    const float* bq = (const float*)d_in[4];
    const float* Wk = (const float*)d_in[5];
    const float* bk = (const float*)d_in[6];
    const float* Wv = (const float*)d_in[7];
    const float* bv = (const float*)d_in[8];
    const float* Wo = (const float*)d_in[9];
    const float* bo = (const float*)d_in[10];
    const float* wa = (const float*)d_in[11];
    const float* wb = (const float*)d_in[12];
    float* out = (float*)d_out;

    char* ws = (char*)d_ws;
    bf16_t* qb   = (bf16_t*)(ws);                 // 8 MB  [8192][512] bf16
    bf16_t* kbuf = (bf16_t*)(ws + 8388608);       // 8 MB
    bf16_t* vbuf = (bf16_t*)(ws + 16777216);      // 8 MB  v standard layout
    bf16_t* vtb  = (bf16_t*)(ws + 25165824);      // 8 MB  vt[g][p][t]
    bf16_t* ctx  = (bf16_t*)(ws + 33554432);      // 8 MB
    bf16_t* xb   = (bf16_t*)(ws + 41943040);      // 8 MB  (total 48 MB)

    gemm_qkv_kernel<<<dim3(4, 64, 3), 256, 0, stream>>>(
        query, key, value, Wq, Wk, Wv, bq, bk, bv, qb, kbuf, vbuf);
    transpose_v_kernel<<<dim3(32, 32), 256, 0, stream>>>(vbuf, vtb);
    attn_kernel<<<dim3(16, 32), 512, 0, stream>>>(qb, kbuf, vtb, out + 4194304, ctx);
    gemm_o_kernel<<<dim3(4, 64), 256, 0, stream>>>(ctx, Wo, bo, query, xb);
    ln_kernel<<<2048, 256, 0, stream>>>(xb, wa, wb, out);
}